// Round 7
// baseline (143.689 us; speedup 1.0000x reference)
//
#include <hip/hip_runtime.h>
#include <hip/hip_bf16.h>

typedef __attribute__((ext_vector_type(8))) short short8;
typedef __attribute__((ext_vector_type(4))) float f32x4;

#define D_   1024
#define SEQ_ 2048
#define NB_  2
#define NH_  16
#define HD_  64
#define LDV_ 4096   // V^T row stride (= B*S)

using u16 = unsigned short;
using u32 = unsigned int;

static __device__ __forceinline__ u16 f2bf(float f) {
    union { __bf16 h; u16 u; } cv;
    cv.h = (__bf16)f;
    return cv.u;
}
static __device__ __forceinline__ float bf2f(u16 u) {
    union { unsigned int i; float f; } v;
    v.i = ((unsigned int)u) << 16;
    return v.f;
}
// pack two f32 -> dword of 2 bf16 (lo = a, hi = b)
static __device__ __forceinline__ u32 pkbf(float a, float b) {
    u32 r;
    asm volatile("v_cvt_pk_bf16_f32 %0, %1, %2" : "=v"(r) : "v"(a), "v"(b));
    return r;
}

// async global->LDS, 16B per lane
static __device__ __forceinline__ void glds16(const u16* g, u16* l) {
    __builtin_amdgcn_global_load_lds(
        (const __attribute__((address_space(1))) unsigned int*)g,
        (__attribute__((address_space(3))) unsigned int*)l, 16, 0, 0);
}

// ---------------- fused f32 -> bf16 convert (one launch for all 5 tensors) ----------------
__global__ __launch_bounds__(256)
void cvt_all(const float* __restrict__ x,  const float* __restrict__ wq,
             const float* __restrict__ wk, const float* __restrict__ wv,
             const float* __restrict__ wo,
             u16* __restrict__ xb,  u16* __restrict__ wqb, u16* __restrict__ wkb,
             u16* __restrict__ wvb, u16* __restrict__ wob)
{
    const int bid = blockIdx.x;
    const float* src; u16* dst; int off;
    if (bid < 2048)      { src = x;  dst = xb;  off = bid; }
    else if (bid < 2560) { src = wq; dst = wqb; off = bid - 2048; }
    else if (bid < 3072) { src = wk; dst = wkb; off = bid - 2560; }
    else if (bid < 3584) { src = wv; dst = wvb; off = bid - 3072; }
    else                 { src = wo; dst = wob; off = bid - 3584; }
    size_t i = ((size_t)off * 256 + threadIdx.x) * 8;
    float4 a = *(const float4*)&src[i];
    float4 b = *(const float4*)&src[i + 4];
    short8 o;
    o[0] = (short)f2bf(a.x); o[1] = (short)f2bf(a.y);
    o[2] = (short)f2bf(a.z); o[3] = (short)f2bf(a.w);
    o[4] = (short)f2bf(b.x); o[5] = (short)f2bf(b.y);
    o[6] = (short)f2bf(b.z); o[7] = (short)f2bf(b.w);
    *(short8*)&dst[i] = o;
}

// ---------------- bf16 GEMM core: Y[m][n] = sum_k A[m][k] * W[n][k] ----------------
// 128x128 tile, BK=32, global_load_lds staging, double-buffered linear LDS (m97 pattern).
template<int OUT_F32>
static __device__ __forceinline__
void gemm_core(const u16* __restrict__ A, const u16* __restrict__ W,
               void* __restrict__ Y, int ldY, int mBase, int nBase,
               u16* lA, u16* lB)
{
    const int t    = threadIdx.x;
    const int lane = t & 63, wid = t >> 6;
    const int wr = wid >> 1, wc = wid & 1;
    const int lr = lane & 15, lg = lane >> 4;

    f32x4 acc[4][4] = {};

    const int srow = t >> 2;         // staging row (+64 for j=1)
    const int scol = (t & 3) * 8;    // staging col (u16)
    const u16* Ag = A + (size_t)(mBase + srow) * D_ + scol;
    const u16* Wg = W + (size_t)(nBase + srow) * D_ + scol;
    const int ldsoff = t * 8;

    auto stage = [&](int buf, int kt) {
#pragma unroll
        for (int j = 0; j < 2; ++j) {
            glds16(Ag + (size_t)j * 64 * D_ + kt * 32, lA + buf * 4096 + j * 2048 + ldsoff);
            glds16(Wg + (size_t)j * 64 * D_ + kt * 32, lB + buf * 4096 + j * 2048 + ldsoff);
        }
    };

    stage(0, 0);
    asm volatile("s_waitcnt vmcnt(0)" ::: "memory");
    __syncthreads();

    int cur = 0;
    for (int kt = 0; kt < 32; ++kt) {
        if (kt < 31) stage(cur ^ 1, kt + 1);
        short8 af[4], bfv[4];
#pragma unroll
        for (int m = 0; m < 4; ++m)
            af[m] = *(const short8*)&lA[cur * 4096 + (wr * 64 + m * 16 + lr) * 32 + lg * 8];
#pragma unroll
        for (int n = 0; n < 4; ++n)
            bfv[n] = *(const short8*)&lB[cur * 4096 + (wc * 64 + n * 16 + lr) * 32 + lg * 8];
#pragma unroll
        for (int m = 0; m < 4; ++m)
#pragma unroll
            for (int n = 0; n < 4; ++n)
                acc[m][n] = __builtin_amdgcn_mfma_f32_16x16x32_bf16(af[m], bfv[n], acc[m][n], 0, 0, 0);
        if (kt < 31) {
            asm volatile("s_waitcnt vmcnt(0)" ::: "memory");
            __syncthreads();
        }
        cur ^= 1;
    }

#pragma unroll
    for (int m = 0; m < 4; ++m)
#pragma unroll
        for (int n = 0; n < 4; ++n)
#pragma unroll
            for (int r = 0; r < 4; ++r) {
                int row = mBase + wr * 64 + m * 16 + lg * 4 + r;
                int col = nBase + wc * 64 + n * 16 + lr;
                if (OUT_F32)
                    ((float*)Y)[(size_t)row * ldY + col] = acc[m][n][r];
                else
                    ((u16*)Y)[(size_t)row * ldY + col] = f2bf(acc[m][n][r]);
            }
}

// fused QKV: z=0 -> Q = x Wq^T, z=1 -> K = x Wk^T, z=2 -> V^T = Wv x^T
__global__ __launch_bounds__(256)
void gemm_qkv(const u16* __restrict__ xb, const u16* __restrict__ wq, const u16* __restrict__ wk,
              const u16* __restrict__ wv, u16* __restrict__ Qo, u16* __restrict__ Ko,
              u16* __restrict__ Vto)
{
    __shared__ u16 lA[2 * 128 * 32];
    __shared__ u16 lB[2 * 128 * 32];
    const int z = blockIdx.z;
    if (z == 0)
        gemm_core<0>(xb, wq, Qo, D_, blockIdx.x * 128, blockIdx.y * 128, lA, lB);
    else if (z == 1)
        gemm_core<0>(xb, wk, Ko, D_, blockIdx.x * 128, blockIdx.y * 128, lA, lB);
    else
        gemm_core<0>(wv, xb, Vto, LDV_, blockIdx.y * 128, blockIdx.x * 128, lA, lB);
}

__global__ __launch_bounds__(256)
void gemm_out(const u16* __restrict__ Ab, const u16* __restrict__ wo, float* __restrict__ out)
{
    __shared__ u16 lA[2 * 128 * 32];
    __shared__ u16 lB[2 * 128 * 32];
    gemm_core<1>(Ab, wo, out, D_, blockIdx.x * 128, blockIdx.y * 128, lA, lB);
}

// ---------------- causal flash attention (round-5 hybrid) ----------------
// 4 waves x 16 q-rows; paired q-tiles (31-x then x) -> 512 uniform blocks;
// swapped-operand softmax (in-register); K LDS-staged double-buffered (4x wave reuse,
// 1 barrier/iter); V loaded direct from L2 at iteration top (consumed ~240cy later).
// bh = blockIdx & 31 -> all 16 blocks of a bh land on one XCD (L2 locality).
__global__ __launch_bounds__(256)
void attn_fwd(const u16* __restrict__ Q, const u16* __restrict__ K,
              const u16* __restrict__ Vt, u16* __restrict__ O)
{
    __shared__ u16 lK[2][64][72];   // [key][hd], 144B stride -> 2-way alias (free)
    __shared__ u16 lP[4][16][72];   // per-wave P: [q][key]

    const int t    = threadIdx.x;
    const int lane = t & 63, wid = t >> 6;
    const int lr = lane & 15, lg = lane >> 4;
    const int id = (int)blockIdx.x;
    const int bh = id & 31;         // id%8 fixed per bh -> XCD-local K/V/Q
    const int px = id >> 5;         // 0..15
    const int b = bh >> 4, h = bh & 15;

    const u16* Qb = Q  + (size_t)b * SEQ_ * D_ + h * HD_;
    const u16* Kb = K  + (size_t)b * SEQ_ * D_ + h * HD_;
    const u16* Vg = Vt + (size_t)(h * HD_) * LDV_ + (size_t)b * SEQ_;
    u16*       Ob = O  + (size_t)b * SEQ_ * D_ + h * HD_;

    const int sr = t >> 3;          // K staging row 0..31 (+32)
    const int sc = (t & 7) * 8;     // K staging col

#pragma unroll 1
    for (int half = 0; half < 2; ++half) {
        const int qt = half ? px : (31 - px);
        const int qbase = qt * 64;
        const int qrow  = qbase + wid * 16 + lr;

        // Q fragment scaled by 0.125*log2(e): softmax in exp2 domain
        short8 qf[2];
#pragma unroll
        for (int ks = 0; ks < 2; ++ks) {
            short8 v = *(const short8*)&Qb[(size_t)qrow * D_ + ks * 32 + lg * 8];
#pragma unroll
            for (int c = 0; c < 8; ++c)
                v[c] = (short)f2bf(bf2f((u16)v[c]) * 0.18033688011112042f);
            qf[ks] = v;
        }

        f32x4 accOT[4] = {};        // O^T: d = n2*16 + lg*4 + j, q = lr (within wave frag)
        float m_r = -1e30f, l_r = 0.f;

        // prologue: stage K tile 0 into buf 0
        {
            short8 k0 = *(const short8*)&Kb[(size_t)sr * D_ + sc];
            short8 k1 = *(const short8*)&Kb[(size_t)(sr + 32) * D_ + sc];
            *(short8*)&lK[0][sr][sc] = k0;  *(short8*)&lK[0][sr + 32][sc] = k1;
        }
        __syncthreads();

        int cur = 0;
        for (int kt = 0; kt <= qt; ++kt) {
            const int kb = kt * 64;

            // V fragments for THIS tile: direct from L2, issued early
            short8 vf0[4], vf1[4];
#pragma unroll
            for (int n2 = 0; n2 < 4; ++n2) {
                vf0[n2] = *(const short8*)&Vg[(size_t)(n2 * 16 + lr) * LDV_ + kb + lg * 8];
                vf1[n2] = *(const short8*)&Vg[(size_t)(n2 * 16 + lr) * LDV_ + kb + 32 + lg * 8];
            }
            // next K tile -> regs (consumed at iteration bottom)
            short8 k0, k1;
            if (kt < qt) {
                const int kn = kb + 64;
                k0 = *(const short8*)&Kb[(size_t)(kn + sr) * D_ + sc];
                k1 = *(const short8*)&Kb[(size_t)(kn + sr + 32) * D_ + sc];
            }

            // S^T = K · Q^T : st[n][j] = S[key = kb+16n+4lg+j][q = qrow]
            f32x4 st[4] = {};
#pragma unroll
            for (int n = 0; n < 4; ++n)
#pragma unroll
                for (int ks = 0; ks < 2; ++ks) {
                    short8 kf = *(const short8*)&lK[cur][n * 16 + lr][ks * 32 + lg * 8];
                    st[n] = __builtin_amdgcn_mfma_f32_16x16x32_bf16(kf, qf[ks], st[n], 0, 0, 0);
                }
            // causal mask (diagonal tile only)
            if (kt == qt) {
#pragma unroll
                for (int n = 0; n < 4; ++n)
#pragma unroll
                    for (int j = 0; j < 4; ++j)
                        if (kb + n * 16 + lg * 4 + j > qrow) st[n][j] = -1e30f;
            }

            // in-register online softmax (exp2 domain); row spans 4 lg-lanes of lr
            float pmax = st[0][0];
#pragma unroll
            for (int n = 0; n < 4; ++n)
#pragma unroll
                for (int j = 0; j < 4; ++j) pmax = fmaxf(pmax, st[n][j]);
            pmax = fmaxf(pmax, __shfl_xor(pmax, 16));
            pmax = fmaxf(pmax, __shfl_xor(pmax, 32));
            const float mn = fmaxf(m_r, pmax);
            const float alpha = exp2f(m_r - mn);
            m_r = mn;
            float rsum = 0.f;
#pragma unroll
            for (int n = 0; n < 4; ++n)
#pragma unroll
                for (int j = 0; j < 4; ++j) {
                    float p = exp2f(st[n][j] - mn);
                    st[n][j] = p;
                    rsum += p;
                }
            rsum += __shfl_xor(rsum, 16);
            rsum += __shfl_xor(rsum, 32);
            l_r = l_r * alpha + rsum;

            // P^T -> lP (rows = q), packed b64 writes; same-wave RAW, no barrier
#pragma unroll
            for (int n = 0; n < 4; ++n) {
                uint2 d;
                d.x = pkbf(st[n][0], st[n][1]);
                d.y = pkbf(st[n][2], st[n][3]);
                *(uint2*)&lP[wid][lr][n * 16 + lg * 4] = d;
            }
#pragma unroll
            for (int n2 = 0; n2 < 4; ++n2)
#pragma unroll
                for (int j = 0; j < 4; ++j) accOT[n2][j] *= alpha;

            // O^T += V^T · P^T  (V from regs, P from per-wave LDS)
            short8 pb0 = *(const short8*)&lP[wid][lr][lg * 8];
            short8 pb1 = *(const short8*)&lP[wid][lr][32 + lg * 8];
#pragma unroll
            for (int n2 = 0; n2 < 4; ++n2) {
                accOT[n2] = __builtin_amdgcn_mfma_f32_16x16x32_bf16(vf0[n2], pb0, accOT[n2], 0, 0, 0);
                accOT[n2] = __builtin_amdgcn_mfma_f32_16x16x32_bf16(vf1[n2], pb1, accOT[n2], 0, 0, 0);
            }

            // stage next K into other buffer
            if (kt < qt) {
                *(short8*)&lK[cur ^ 1][sr][sc] = k0;
                *(short8*)&lK[cur ^ 1][sr + 32][sc] = k1;
            }
            __syncthreads();
            cur ^= 1;
        }

        // epilogue: O[q][d] = O^T[d][q] / l (packed dword writes)
        const float inv = 1.f / l_r;
#pragma unroll
        for (int n2 = 0; n2 < 4; ++n2) {
            *(u32*)&Ob[(size_t)qrow * D_ + n2 * 16 + lg * 4]     = pkbf(accOT[n2][0] * inv, accOT[n2][1] * inv);
            *(u32*)&Ob[(size_t)qrow * D_ + n2 * 16 + lg * 4 + 2] = pkbf(accOT[n2][2] * inv, accOT[n2][3] * inv);
        }
        // final loop-iteration barrier already separates halves
    }
}

extern "C" void kernel_launch(void* const* d_in, const int* in_sizes, int n_in,
                              void* d_out, int out_size, void* d_ws, size_t ws_size,
                              hipStream_t stream)
{
    const float* x  = (const float*)d_in[0];
    const float* Wq = (const float*)d_in[1];
    const float* Wk = (const float*)d_in[2];
    const float* Wv = (const float*)d_in[3];
    const float* Wo = (const float*)d_in[4];
    float* out = (float*)d_out;

    const size_t NX = (size_t)NB_ * SEQ_ * D_;  // 4194304
    const size_t NW = (size_t)D_ * D_;          // 1048576

    u16* xb  = (u16*)d_ws;
    u16* wqb = xb  + NX;
    u16* wkb = wqb + NW;
    u16* wvb = wkb + NW;
    u16* wob = wvb + NW;
    u16* Qb  = wob + NW;
    u16* Kb  = Qb  + NX;
    u16* Vtb = Kb  + NX;   // V^T: [1024][4096]
    u16* Ab  = Vtb + NX;

    cvt_all<<<dim3(4096), dim3(256), 0, stream>>>(x, Wq, Wk, Wv, Wo,
                                                  xb, wqb, wkb, wvb, wob);

    gemm_qkv<<<dim3(32, 8, 3), dim3(256), 0, stream>>>(xb, wqb, wkb, wvb, Qb, Kb, Vtb);

    // paired q-tiles: 512 uniform blocks; bh = id&31 keeps each bh on one XCD
    attn_fwd<<<dim3(512), dim3(256), 0, stream>>>(Qb, Kb, Vtb, Ab);

    gemm_out<<<dim3(32, 8, 1), dim3(256), 0, stream>>>(Ab, wob, out);
}

// Round 8
// 143.345 us; speedup vs baseline: 1.0024x; 1.0024x over previous
//
#include <hip/hip_runtime.h>
#include <hip/hip_bf16.h>

typedef __attribute__((ext_vector_type(8))) short short8;
typedef __attribute__((ext_vector_type(4))) float f32x4;

#define D_   1024
#define SEQ_ 2048
#define NB_  2
#define NH_  16
#define HD_  64
#define LDV_ 4096   // V^T row stride (= B*S)

using u16 = unsigned short;
using u32 = unsigned int;

static __device__ __forceinline__ u16 f2bf(float f) {
    union { __bf16 h; u16 u; } cv;
    cv.h = (__bf16)f;
    return cv.u;
}
static __device__ __forceinline__ float bf2f(u16 u) {
    union { unsigned int i; float f; } v;
    v.i = ((unsigned int)u) << 16;
    return v.f;
}
// pack two f32 -> dword of 2 bf16 (lo = a, hi = b)
static __device__ __forceinline__ u32 pkbf(float a, float b) {
    u32 r;
    asm volatile("v_cvt_pk_bf16_f32 %0, %1, %2" : "=v"(r) : "v"(a), "v"(b));
    return r;
}

// async global->LDS, 16B per lane
static __device__ __forceinline__ void glds16(const u16* g, u16* l) {
    __builtin_amdgcn_global_load_lds(
        (const __attribute__((address_space(1))) unsigned int*)g,
        (__attribute__((address_space(3))) unsigned int*)l, 16, 0, 0);
}

// ---------------- fused f32 -> bf16 convert (one launch for all 5 tensors) ----------------
__global__ __launch_bounds__(256)
void cvt_all(const float* __restrict__ x,  const float* __restrict__ wq,
             const float* __restrict__ wk, const float* __restrict__ wv,
             const float* __restrict__ wo,
             u16* __restrict__ xb,  u16* __restrict__ wqb, u16* __restrict__ wkb,
             u16* __restrict__ wvb, u16* __restrict__ wob)
{
    const int bid = blockIdx.x;
    const float* src; u16* dst; int off;
    if (bid < 2048)      { src = x;  dst = xb;  off = bid; }
    else if (bid < 2560) { src = wq; dst = wqb; off = bid - 2048; }
    else if (bid < 3072) { src = wk; dst = wkb; off = bid - 2560; }
    else if (bid < 3584) { src = wv; dst = wvb; off = bid - 3072; }
    else                 { src = wo; dst = wob; off = bid - 3584; }
    size_t i = ((size_t)off * 256 + threadIdx.x) * 8;
    float4 a = *(const float4*)&src[i];
    float4 b = *(const float4*)&src[i + 4];
    short8 o;
    o[0] = (short)f2bf(a.x); o[1] = (short)f2bf(a.y);
    o[2] = (short)f2bf(a.z); o[3] = (short)f2bf(a.w);
    o[4] = (short)f2bf(b.x); o[5] = (short)f2bf(b.y);
    o[6] = (short)f2bf(b.z); o[7] = (short)f2bf(b.w);
    *(short8*)&dst[i] = o;
}

// ---------------- bf16 GEMM core: Y[m][n] = sum_k A[m][k] * W[n][k] ----------------
// 128x128 tile, BK=32, global_load_lds staging, double-buffered linear LDS (m97 pattern).
template<int OUT_F32>
static __device__ __forceinline__
void gemm_core(const u16* __restrict__ A, const u16* __restrict__ W,
               void* __restrict__ Y, int ldY, int mBase, int nBase,
               u16* lA, u16* lB)
{
    const int t    = threadIdx.x;
    const int lane = t & 63, wid = t >> 6;
    const int wr = wid >> 1, wc = wid & 1;
    const int lr = lane & 15, lg = lane >> 4;

    f32x4 acc[4][4] = {};

    const int srow = t >> 2;         // staging row (+64 for j=1)
    const int scol = (t & 3) * 8;    // staging col (u16)
    const u16* Ag = A + (size_t)(mBase + srow) * D_ + scol;
    const u16* Wg = W + (size_t)(nBase + srow) * D_ + scol;
    const int ldsoff = t * 8;

    auto stage = [&](int buf, int kt) {
#pragma unroll
        for (int j = 0; j < 2; ++j) {
            glds16(Ag + (size_t)j * 64 * D_ + kt * 32, lA + buf * 4096 + j * 2048 + ldsoff);
            glds16(Wg + (size_t)j * 64 * D_ + kt * 32, lB + buf * 4096 + j * 2048 + ldsoff);
        }
    };

    stage(0, 0);
    asm volatile("s_waitcnt vmcnt(0)" ::: "memory");
    __syncthreads();

    int cur = 0;
    for (int kt = 0; kt < 32; ++kt) {
        if (kt < 31) stage(cur ^ 1, kt + 1);
        short8 af[4], bfv[4];
#pragma unroll
        for (int m = 0; m < 4; ++m)
            af[m] = *(const short8*)&lA[cur * 4096 + (wr * 64 + m * 16 + lr) * 32 + lg * 8];
#pragma unroll
        for (int n = 0; n < 4; ++n)
            bfv[n] = *(const short8*)&lB[cur * 4096 + (wc * 64 + n * 16 + lr) * 32 + lg * 8];
#pragma unroll
        for (int m = 0; m < 4; ++m)
#pragma unroll
            for (int n = 0; n < 4; ++n)
                acc[m][n] = __builtin_amdgcn_mfma_f32_16x16x32_bf16(af[m], bfv[n], acc[m][n], 0, 0, 0);
        if (kt < 31) {
            asm volatile("s_waitcnt vmcnt(0)" ::: "memory");
            __syncthreads();
        }
        cur ^= 1;
    }

#pragma unroll
    for (int m = 0; m < 4; ++m)
#pragma unroll
        for (int n = 0; n < 4; ++n)
#pragma unroll
            for (int r = 0; r < 4; ++r) {
                int row = mBase + wr * 64 + m * 16 + lg * 4 + r;
                int col = nBase + wc * 64 + n * 16 + lr;
                if (OUT_F32)
                    ((float*)Y)[(size_t)row * ldY + col] = acc[m][n][r];
                else
                    ((u16*)Y)[(size_t)row * ldY + col] = f2bf(acc[m][n][r]);
            }
}

// fused QKV: z=0 -> Q = x Wq^T, z=1 -> K = x Wk^T, z=2 -> V^T = Wv x^T
__global__ __launch_bounds__(256)
void gemm_qkv(const u16* __restrict__ xb, const u16* __restrict__ wq, const u16* __restrict__ wk,
              const u16* __restrict__ wv, u16* __restrict__ Qo, u16* __restrict__ Ko,
              u16* __restrict__ Vto)
{
    __shared__ u16 lA[2 * 128 * 32];
    __shared__ u16 lB[2 * 128 * 32];
    const int z = blockIdx.z;
    if (z == 0)
        gemm_core<0>(xb, wq, Qo, D_, blockIdx.x * 128, blockIdx.y * 128, lA, lB);
    else if (z == 1)
        gemm_core<0>(xb, wk, Ko, D_, blockIdx.x * 128, blockIdx.y * 128, lA, lB);
    else
        gemm_core<0>(wv, xb, Vto, LDV_, blockIdx.y * 128, blockIdx.x * 128, lA, lB);
}

__global__ __launch_bounds__(256)
void gemm_out(const u16* __restrict__ Ab, const u16* __restrict__ wo, float* __restrict__ out)
{
    __shared__ u16 lA[2 * 128 * 32];
    __shared__ u16 lB[2 * 128 * 32];
    gemm_core<1>(Ab, wo, out, D_, blockIdx.x * 128, blockIdx.y * 128, lA, lB);
}

// ---------------- causal flash attention (round-5 hybrid) ----------------
// 4 waves x 16 q-rows; paired q-tiles (31-x then x) -> 512 uniform blocks;
// swapped-operand softmax (in-register); K LDS-staged double-buffered (4x wave reuse,
// 1 barrier/iter); V loaded direct from L2 at iteration top (consumed ~240cy later).
// bh = blockIdx & 31 -> all 16 blocks of a bh land on one XCD (L2 locality).
__global__ __launch_bounds__(256)
void attn_fwd(const u16* __restrict__ Q, const u16* __restrict__ K,
              const u16* __restrict__ Vt, u16* __restrict__ O)
{
    __shared__ u16 lK[2][64][72];   // [key][hd], 144B stride -> 2-way alias (free)
    __shared__ u16 lP[4][16][72];   // per-wave P: [q][key]

    const int t    = threadIdx.x;
    const int lane = t & 63, wid = t >> 6;
    const int lr = lane & 15, lg = lane >> 4;
    const int id = (int)blockIdx.x;
    const int bh = id & 31;         // id%8 fixed per bh -> XCD-local K/V/Q
    const int px = id >> 5;         // 0..15
    const int b = bh >> 4, h = bh & 15;

    const u16* Qb = Q  + (size_t)b * SEQ_ * D_ + h * HD_;
    const u16* Kb = K  + (size_t)b * SEQ_ * D_ + h * HD_;
    const u16* Vg = Vt + (size_t)(h * HD_) * LDV_ + (size_t)b * SEQ_;
    u16*       Ob = O  + (size_t)b * SEQ_ * D_ + h * HD_;

    const int sr = t >> 3;          // K staging row 0..31 (+32)
    const int sc = (t & 7) * 8;     // K staging col

#pragma unroll 1
    for (int half = 0; half < 2; ++half) {
        const int qt = half ? px : (31 - px);
        const int qbase = qt * 64;
        const int qrow  = qbase + wid * 16 + lr;

        // Q fragment scaled by 0.125*log2(e): softmax in exp2 domain
        short8 qf[2];
#pragma unroll
        for (int ks = 0; ks < 2; ++ks) {
            short8 v = *(const short8*)&Qb[(size_t)qrow * D_ + ks * 32 + lg * 8];
#pragma unroll
            for (int c = 0; c < 8; ++c)
                v[c] = (short)f2bf(bf2f((u16)v[c]) * 0.18033688011112042f);
            qf[ks] = v;
        }

        f32x4 accOT[4] = {};        // O^T: d = n2*16 + lg*4 + j, q = lr (within wave frag)
        float m_r = -1e30f, l_r = 0.f;

        // prologue: stage K tile 0 into buf 0
        {
            short8 k0 = *(const short8*)&Kb[(size_t)sr * D_ + sc];
            short8 k1 = *(const short8*)&Kb[(size_t)(sr + 32) * D_ + sc];
            *(short8*)&lK[0][sr][sc] = k0;  *(short8*)&lK[0][sr + 32][sc] = k1;
        }
        __syncthreads();

        int cur = 0;
        for (int kt = 0; kt <= qt; ++kt) {
            const int kb = kt * 64;

            // V fragments for THIS tile: direct from L2, issued early
            short8 vf0[4], vf1[4];
#pragma unroll
            for (int n2 = 0; n2 < 4; ++n2) {
                vf0[n2] = *(const short8*)&Vg[(size_t)(n2 * 16 + lr) * LDV_ + kb + lg * 8];
                vf1[n2] = *(const short8*)&Vg[(size_t)(n2 * 16 + lr) * LDV_ + kb + 32 + lg * 8];
            }
            // next K tile -> regs (consumed at iteration bottom)
            short8 k0, k1;
            if (kt < qt) {
                const int kn = kb + 64;
                k0 = *(const short8*)&Kb[(size_t)(kn + sr) * D_ + sc];
                k1 = *(const short8*)&Kb[(size_t)(kn + sr + 32) * D_ + sc];
            }

            // S^T = K · Q^T : st[n][j] = S[key = kb+16n+4lg+j][q = qrow]
            f32x4 st[4] = {};
#pragma unroll
            for (int n = 0; n < 4; ++n)
#pragma unroll
                for (int ks = 0; ks < 2; ++ks) {
                    short8 kf = *(const short8*)&lK[cur][n * 16 + lr][ks * 32 + lg * 8];
                    st[n] = __builtin_amdgcn_mfma_f32_16x16x32_bf16(kf, qf[ks], st[n], 0, 0, 0);
                }
            // causal mask (diagonal tile only)
            if (kt == qt) {
#pragma unroll
                for (int n = 0; n < 4; ++n)
#pragma unroll
                    for (int j = 0; j < 4; ++j)
                        if (kb + n * 16 + lg * 4 + j > qrow) st[n][j] = -1e30f;
            }

            // in-register online softmax (exp2 domain); row spans 4 lg-lanes of lr
            float pmax = st[0][0];
#pragma unroll
            for (int n = 0; n < 4; ++n)
#pragma unroll
                for (int j = 0; j < 4; ++j) pmax = fmaxf(pmax, st[n][j]);
            pmax = fmaxf(pmax, __shfl_xor(pmax, 16));
            pmax = fmaxf(pmax, __shfl_xor(pmax, 32));
            const float mn = fmaxf(m_r, pmax);
            const float alpha = exp2f(m_r - mn);
            m_r = mn;
            float rsum = 0.f;
#pragma unroll
            for (int n = 0; n < 4; ++n)
#pragma unroll
                for (int j = 0; j < 4; ++j) {
                    float p = exp2f(st[n][j] - mn);
                    st[n][j] = p;
                    rsum += p;
                }
            rsum += __shfl_xor(rsum, 16);
            rsum += __shfl_xor(rsum, 32);
            l_r = l_r * alpha + rsum;

            // P^T -> lP (rows = q), packed b64 writes; same-wave RAW, no barrier
#pragma unroll
            for (int n = 0; n < 4; ++n) {
                uint2 d;
                d.x = pkbf(st[n][0], st[n][1]);
                d.y = pkbf(st[n][2], st[n][3]);
                *(uint2*)&lP[wid][lr][n * 16 + lg * 4] = d;
            }
#pragma unroll
            for (int n2 = 0; n2 < 4; ++n2)
#pragma unroll
                for (int j = 0; j < 4; ++j) accOT[n2][j] *= alpha;

            // O^T += V^T · P^T  (V from regs, P from per-wave LDS)
            short8 pb0 = *(const short8*)&lP[wid][lr][lg * 8];
            short8 pb1 = *(const short8*)&lP[wid][lr][32 + lg * 8];
#pragma unroll
            for (int n2 = 0; n2 < 4; ++n2) {
                accOT[n2] = __builtin_amdgcn_mfma_f32_16x16x32_bf16(vf0[n2], pb0, accOT[n2], 0, 0, 0);
                accOT[n2] = __builtin_amdgcn_mfma_f32_16x16x32_bf16(vf1[n2], pb1, accOT[n2], 0, 0, 0);
            }

            // stage next K into other buffer
            if (kt < qt) {
                *(short8*)&lK[cur ^ 1][sr][sc] = k0;
                *(short8*)&lK[cur ^ 1][sr + 32][sc] = k1;
            }
            __syncthreads();
            cur ^= 1;
        }

        // epilogue: O[q][d] = O^T[d][q] / l (packed dword writes)
        const float inv = 1.f / l_r;
#pragma unroll
        for (int n2 = 0; n2 < 4; ++n2) {
            *(u32*)&Ob[(size_t)qrow * D_ + n2 * 16 + lg * 4]     = pkbf(accOT[n2][0] * inv, accOT[n2][1] * inv);
            *(u32*)&Ob[(size_t)qrow * D_ + n2 * 16 + lg * 4 + 2] = pkbf(accOT[n2][2] * inv, accOT[n2][3] * inv);
        }
        // final loop-iteration barrier already separates halves
    }
}

extern "C" void kernel_launch(void* const* d_in, const int* in_sizes, int n_in,
                              void* d_out, int out_size, void* d_ws, size_t ws_size,
                              hipStream_t stream)
{
    const float* x  = (const float*)d_in[0];
    const float* Wq = (const float*)d_in[1];
    const float* Wk = (const float*)d_in[2];
    const float* Wv = (const float*)d_in[3];
    const float* Wo = (const float*)d_in[4];
    float* out = (float*)d_out;

    const size_t NX = (size_t)NB_ * SEQ_ * D_;  // 4194304
    const size_t NW = (size_t)D_ * D_;          // 1048576

    u16* xb  = (u16*)d_ws;
    u16* wqb = xb  + NX;
    u16* wkb = wqb + NW;
    u16* wvb = wkb + NW;
    u16* wob = wvb + NW;
    u16* Qb  = wob + NW;
    u16* Kb  = Qb  + NX;
    u16* Vtb = Kb  + NX;   // V^T: [1024][4096]
    u16* Ab  = Vtb + NX;

    cvt_all<<<dim3(4096), dim3(256), 0, stream>>>(x, Wq, Wk, Wv, Wo,
                                                  xb, wqb, wkb, wvb, wob);

    gemm_qkv<<<dim3(32, 8, 3), dim3(256), 0, stream>>>(xb, wqb, wkb, wvb, Qb, Kb, Vtb);

    // paired q-tiles: 512 uniform blocks; bh = id&31 keeps each bh on one XCD
    attn_fwd<<<dim3(512), dim3(256), 0, stream>>>(Qb, Kb, Vtb, Ab);

    gemm_out<<<dim3(32, 8, 1), dim3(256), 0, stream>>>(Ab, wob, out);
}